// Round 4
// baseline (826.323 us; speedup 1.0000x reference)
//
#include <hip/hip_runtime.h>
#include <hip/hip_bf16.h>

typedef unsigned short u16;
typedef unsigned int u32;
typedef __attribute__((ext_vector_type(8))) short short8;   // 8 bf16 (4 VGPRs) MFMA A/B frag
typedef __attribute__((ext_vector_type(4))) float f32x4;    // MFMA C/D frag

__device__ __forceinline__ float bf2f(u16 u) {
    union { u32 i; float f; } v; v.i = ((u32)u) << 16; return v.f;
}
__device__ __forceinline__ u16 f2bf(float f) {            // RNE (used in G/Y1 producers)
    union { float f; u32 i; } v; v.f = f;
    u32 r = v.i + 0x7fffu + ((v.i >> 16) & 1u);
    return (u16)(r >> 16);
}
// pack two f32 -> two bf16 (truncation) in ONE v_perm
__device__ __forceinline__ u32 pack_bf2(float lo, float hi) {
    return __builtin_amdgcn_perm(__float_as_uint(hi), __float_as_uint(lo), 0x07060302u);
}
// within-wave LDS write->read fence (per-wave regions only)
__device__ __forceinline__ void lds_fence() {
    __asm__ __volatile__("s_waitcnt lgkmcnt(0)" ::: "memory");
}

// ---------------------------------------------------------------------------
// Fused projection + gate precompute (layer 1 entry):
//   xp = relu(X@pw^T + pb); G = xp@wih^T + bih + bhh
// ---------------------------------------------------------------------------
__global__ __launch_bounds__(256) void proj_gates_kernel(
    const u16* __restrict__ X,    // [M,64]
    const u16* __restrict__ pw,   // [64,64]
    const u16* __restrict__ pb,   // [64]
    const u16* __restrict__ wih,  // [256,64]
    const u16* __restrict__ bih, const u16* __restrict__ bhh, // [256]
    u16* __restrict__ G,          // [M,256]
    int M)
{
    __shared__ u16 xp_lds[4][16 * 64];

    const int lane = threadIdx.x & 63;
    const int wave = threadIdx.x >> 6;
    const int row0 = (blockIdx.x * 4 + wave) * 16;
    if (row0 >= M) return;
    const int col  = lane & 15;
    const int quad = lane >> 4;
    u16* xl = xp_lds[wave];

    // GEMM1: xp
    f32x4 c1[4];
#pragma unroll
    for (int jt = 0; jt < 4; ++jt) c1[jt] = (f32x4){0.f, 0.f, 0.f, 0.f};
    {
        const u16* xrow = X  + (size_t)(row0 + col) * 64 + quad * 8;
        const u16* wrow = pw + (size_t)col * 64 + quad * 8;
#pragma unroll
        for (int kc = 0; kc < 64; kc += 32) {
            short8 a = *(const short8*)(xrow + kc);
#pragma unroll
            for (int jt = 0; jt < 4; ++jt) {
                short8 b = *(const short8*)(wrow + (size_t)jt * 16 * 64 + kc);
                c1[jt] = __builtin_amdgcn_mfma_f32_16x16x32_bf16(a, b, c1[jt], 0, 0, 0);
            }
        }
    }
#pragma unroll
    for (int jt = 0; jt < 4; ++jt) {
        float bias = bf2f(pb[jt * 16 + col]);
#pragma unroll
        for (int r = 0; r < 4; ++r) {
            float v = fmaxf(c1[jt][r] + bias, 0.f);
            int row = quad * 4 + r;
            int k   = jt * 16 + col;
            xl[row * 64 + ((((k >> 3) ^ (row & 7))) << 3) + (k & 7)] = f2bf(v);
        }
    }
    lds_fence();

    // GEMM2: G^T = wih @ xp^T
    short8 b0, b1v;
    {
        int c0  = (0 * 4 + quad) ^ (col & 7);
        int c1i = (1 * 4 + quad) ^ (col & 7);
        b0  = *(const short8*)(xl + col * 64 + c0 * 8);
        b1v = *(const short8*)(xl + col * 64 + c1i * 8);
    }
#pragma unroll
    for (int jt = 0; jt < 16; ++jt) {
        f32x4 acc;
        {
            uint2 u1 = *(const uint2*)(bih + jt * 16 + quad * 4);
            uint2 u2 = *(const uint2*)(bhh + jt * 16 + quad * 4);
            acc[0] = bf2f((u16)(u1.x & 0xffffu)) + bf2f((u16)(u2.x & 0xffffu));
            acc[1] = bf2f((u16)(u1.x >> 16))     + bf2f((u16)(u2.x >> 16));
            acc[2] = bf2f((u16)(u1.y & 0xffffu)) + bf2f((u16)(u2.y & 0xffffu));
            acc[3] = bf2f((u16)(u1.y >> 16))     + bf2f((u16)(u2.y >> 16));
        }
        const u16* arow = wih + (size_t)(jt * 16 + col) * 64 + quad * 8;
        short8 a0 = *(const short8*)(arow);
        acc = __builtin_amdgcn_mfma_f32_16x16x32_bf16(a0, b0, acc, 0, 0, 0);
        short8 a1 = *(const short8*)(arow + 32);
        acc = __builtin_amdgcn_mfma_f32_16x16x32_bf16(a1, b1v, acc, 0, 0, 0);
        uint2 o;
        o.x = (u32)f2bf(acc[0]) | ((u32)f2bf(acc[1]) << 16);
        o.y = (u32)f2bf(acc[2]) | ((u32)f2bf(acc[3]) << 16);
        *(uint2*)(G + (size_t)(row0 + col) * 256 + jt * 16 + quad * 4) = o;
    }
}

// ---------------------------------------------------------------------------
// Fused: Y1 = relu(H@llw^T + X2@lrw^T + llb)  -> global (needed later) + LDS
//        xp = relu(Y1@pw^T + pb)              -> LDS
//        G  = xp@wih^T + bih + bhh            -> global
// ---------------------------------------------------------------------------
__global__ __launch_bounds__(256) void epi_pg_kernel(
    const u16* __restrict__ H, const u16* __restrict__ X2,       // [M,64]
    const u16* __restrict__ llw, const u16* __restrict__ llb,
    const u16* __restrict__ lrw,                                 // [64,64],[64],[64,64]
    const u16* __restrict__ pw, const u16* __restrict__ pb,      // [64,64],[64]
    const u16* __restrict__ wih,
    const u16* __restrict__ bih, const u16* __restrict__ bhh,    // [256,64],[256],[256]
    u16* __restrict__ Y1, u16* __restrict__ G, int M)
{
    __shared__ u16 t_lds[4][16 * 64];

    const int lane = threadIdx.x & 63;
    const int wave = threadIdx.x >> 6;
    const int row0 = (blockIdx.x * 4 + wave) * 16;
    if (row0 >= M) return;
    const int col  = lane & 15;
    const int quad = lane >> 4;
    u16* tl = t_lds[wave];

    // GEMM0: dual K=64
    f32x4 c0[4];
#pragma unroll
    for (int jt = 0; jt < 4; ++jt) c0[jt] = (f32x4){0.f, 0.f, 0.f, 0.f};
#pragma unroll
    for (int pass = 0; pass < 2; ++pass) {
        const u16* Xp = pass ? X2 : H;
        const u16* Wp = pass ? lrw : llw;
        const u16* xrow = Xp + (size_t)(row0 + col) * 64 + quad * 8;
        const u16* wrow = Wp + (size_t)col * 64 + quad * 8;
#pragma unroll
        for (int kc = 0; kc < 64; kc += 32) {
            short8 a = *(const short8*)(xrow + kc);
#pragma unroll
            for (int jt = 0; jt < 4; ++jt) {
                short8 b = *(const short8*)(wrow + (size_t)jt * 16 * 64 + kc);
                c0[jt] = __builtin_amdgcn_mfma_f32_16x16x32_bf16(a, b, c0[jt], 0, 0, 0);
            }
        }
    }
#pragma unroll
    for (int jt = 0; jt < 4; ++jt) {
        float bias = bf2f(llb[jt * 16 + col]);
#pragma unroll
        for (int r = 0; r < 4; ++r) {
            float v = fmaxf(c0[jt][r] + bias, 0.f);
            u16 vb = f2bf(v);
            int row = quad * 4 + r;
            int k   = jt * 16 + col;
            Y1[(size_t)(row0 + row) * 64 + k] = vb;
            tl[row * 64 + ((((k >> 3) ^ (row & 7))) << 3) + (k & 7)] = vb;
        }
    }
    lds_fence();

    // GEMM1: xp = relu(Y1@pw^T + pb); A from LDS
    short8 a0f, a1f;
    {
        int c0i = (0 * 4 + quad) ^ (col & 7);
        int c1i = (1 * 4 + quad) ^ (col & 7);
        a0f = *(const short8*)(tl + col * 64 + c0i * 8);
        a1f = *(const short8*)(tl + col * 64 + c1i * 8);
    }
    // NOTE: here A-frag = Y1 rows (m=col), B = pw rows. Lane's A data = its own row.
    f32x4 c1[4];
#pragma unroll
    for (int jt = 0; jt < 4; ++jt) c1[jt] = (f32x4){0.f, 0.f, 0.f, 0.f};
    {
        // rebuild standard A-frag: lane needs row (l&15), k = quad*8..; that is
        // exactly what a0f/a1f hold (chunks quad, quad+4 of row col).
        const u16* wrow = pw + (size_t)col * 64 + quad * 8;
#pragma unroll
        for (int jt = 0; jt < 4; ++jt) {
            short8 b0 = *(const short8*)(wrow + (size_t)jt * 16 * 64);
            c1[jt] = __builtin_amdgcn_mfma_f32_16x16x32_bf16(a0f, b0, c1[jt], 0, 0, 0);
            short8 b1 = *(const short8*)(wrow + (size_t)jt * 16 * 64 + 32);
            c1[jt] = __builtin_amdgcn_mfma_f32_16x16x32_bf16(a1f, b1, c1[jt], 0, 0, 0);
        }
    }
#pragma unroll
    for (int jt = 0; jt < 4; ++jt) {
        float bias = bf2f(pb[jt * 16 + col]);
#pragma unroll
        for (int r = 0; r < 4; ++r) {
            float v = fmaxf(c1[jt][r] + bias, 0.f);
            int row = quad * 4 + r;
            int k   = jt * 16 + col;
            tl[row * 64 + ((((k >> 3) ^ (row & 7))) << 3) + (k & 7)] = f2bf(v);
        }
    }
    lds_fence();

    // GEMM2: gates (identical to proj_gates GEMM2)
    short8 b0, b1v;
    {
        int c0i = (0 * 4 + quad) ^ (col & 7);
        int c1i = (1 * 4 + quad) ^ (col & 7);
        b0  = *(const short8*)(tl + col * 64 + c0i * 8);
        b1v = *(const short8*)(tl + col * 64 + c1i * 8);
    }
#pragma unroll
    for (int jt = 0; jt < 16; ++jt) {
        f32x4 acc;
        {
            uint2 u1 = *(const uint2*)(bih + jt * 16 + quad * 4);
            uint2 u2 = *(const uint2*)(bhh + jt * 16 + quad * 4);
            acc[0] = bf2f((u16)(u1.x & 0xffffu)) + bf2f((u16)(u2.x & 0xffffu));
            acc[1] = bf2f((u16)(u1.x >> 16))     + bf2f((u16)(u2.x >> 16));
            acc[2] = bf2f((u16)(u1.y & 0xffffu)) + bf2f((u16)(u2.y & 0xffffu));
            acc[3] = bf2f((u16)(u1.y >> 16))     + bf2f((u16)(u2.y >> 16));
        }
        const u16* arow = wih + (size_t)(jt * 16 + col) * 64 + quad * 8;
        short8 a0 = *(const short8*)(arow);
        acc = __builtin_amdgcn_mfma_f32_16x16x32_bf16(a0, b0, acc, 0, 0, 0);
        short8 a1 = *(const short8*)(arow + 32);
        acc = __builtin_amdgcn_mfma_f32_16x16x32_bf16(a1, b1v, acc, 0, 0, 0);
        uint2 o;
        o.x = (u32)f2bf(acc[0]) | ((u32)f2bf(acc[1]) << 16);
        o.y = (u32)f2bf(acc[2]) | ((u32)f2bf(acc[3]) << 16);
        *(uint2*)(G + (size_t)(row0 + col) * 256 + jt * 16 + quad * 4) = o;
    }
}

// ---------------------------------------------------------------------------
// LSTM aggregation. Prefetched G gather; idx via shuffle; merged-rcp nonlin.
// ---------------------------------------------------------------------------
__global__ __launch_bounds__(256, 3) void lstm_kernel(
    const u16* __restrict__ G,     // [N,256] (bih+bhh folded)
    const int* __restrict__ src,   // [N*16]
    const u16* __restrict__ whh,   // [256,64]
    u16* __restrict__ Hout,        // [N,64]
    int N)
{
    __shared__ u16 lds_whh[32 * 64 * 8];     // 32KB
    __shared__ u16 lds_h[4][2 * 64 * 8];     // 8KB total
    // 40KB/block

    const int tid  = threadIdx.x;
    const int lane = tid & 63;
    const int wave = tid >> 6;
    const int col  = lane & 15;
    const int quad = lane >> 4;

    const int node0 = (blockIdx.x * 4 + wave) * 16;
    const bool active = node0 < N;   // N%16==0 -> whole wave uniform

    // per-lane: indices for node `col`, steps quad*4 .. quad*4+3
    int4 sidx = active ? *(const int4*)(src + (size_t)(node0 + col) * 16 + quad * 4)
                       : (int4){0, 0, 0, 0};

    // t=0 index + G prefetch (overlaps whh staging + barrier)
    uint2 gbuf[16];
    {
        int s0 = __shfl(sidx.x, col, 64);
        const u16* g0 = G + (size_t)s0 * 256 + quad * 4;
#pragma unroll
        for (int jt = 0; jt < 16; ++jt) gbuf[jt] = *(const uint2*)(g0 + jt * 16);
    }

    // Stage Whh into LDS in fragment order
    for (int s = tid; s < 32 * 64; s += 256) {
        int f = s >> 6, l = s & 63;
        int jt = f >> 1, kc = f & 1;
        int row = jt * 16 + (l & 15);
        int k0  = kc * 32 + (l >> 4) * 8;
        *(short8*)(lds_whh + (size_t)s * 8) = *(const short8*)(whh + row * 64 + k0);
    }
    __syncthreads();
    if (!active) return;
    // waves independent from here (own lds_h region; lds_whh read-only)

    u16* myh = lds_h[wave];

    float c_[16];
#pragma unroll
    for (int i = 0; i < 16; ++i) c_[i] = 0.f;

    for (int t = 0; t < 16; ++t) {
        // 1) convert current G into accumulators
        f32x4 acc[16];
#pragma unroll
        for (int jt = 0; jt < 16; ++jt) {
            uint2 g2 = gbuf[jt];
            f32x4 a;
            a[0] = __uint_as_float(g2.x << 16);
            a[1] = __uint_as_float(g2.x & 0xffff0000u);
            a[2] = __uint_as_float(g2.y << 16);
            a[3] = __uint_as_float(g2.y & 0xffff0000u);
            acc[jt] = a;
        }
        // 2) prefetch t+1 (index via shuffle)
        if (t < 15) {
            int tn = t + 1;
            int cv = (tn & 2) ? ((tn & 1) ? sidx.w : sidx.z)
                              : ((tn & 1) ? sidx.y : sidx.x);
            int sn = __shfl(cv, ((tn >> 2) << 4) + col, 64);
            const u16* gn = G + (size_t)sn * 256 + quad * 4;
#pragma unroll
            for (int jt = 0; jt < 16; ++jt) gbuf[jt] = *(const uint2*)(gn + jt * 16);
        }
        // 3) recurrent GEMM
        if (t > 0) {
            short8 hb0 = *(const short8*)(myh + (size_t)(0 * 64 + lane) * 8);
            short8 hb1 = *(const short8*)(myh + (size_t)(1 * 64 + lane) * 8);
#pragma unroll
            for (int jt = 0; jt < 16; ++jt) {
                short8 a0 = *(const short8*)(lds_whh + (size_t)((jt * 2 + 0) * 64 + lane) * 8);
                acc[jt] = __builtin_amdgcn_mfma_f32_16x16x32_bf16(a0, hb0, acc[jt], 0, 0, 0);
                short8 a1 = *(const short8*)(lds_whh + (size_t)((jt * 2 + 1) * 64 + lane) * 8);
                acc[jt] = __builtin_amdgcn_mfma_f32_16x16x32_bf16(a1, hb1, acc[jt], 0, 0, 0);
            }
        }
        // 4) nonlinearity: c=sig(f)c+sig(i)tanh(g); h=sig(o)tanh(c)
        //    sig(i)tanh(g) = (e2g-1)/((1+e^-i)(1+e2g)); same merge for o,c.
#pragma unroll
        for (int u = 0; u < 4; ++u) {
            u32 hp[2];
#pragma unroll
            for (int pr = 0; pr < 2; ++pr) {
                float hv[2];
#pragma unroll
                for (int q = 0; q < 2; ++q) {
                    int r = pr * 2 + q;
                    float iv = acc[u +  0][r];
                    float fv = acc[u +  4][r];
                    float gv = acc[u +  8][r];
                    float ov = acc[u + 12][r];
                    float ei = __expf(-iv);
                    float ef = __expf(-fv);
                    float eg = __expf(2.0f * gv);
                    float eo = __expf(-ov);
                    float sf  = __builtin_amdgcn_rcpf(1.0f + ef);
                    float rig = __builtin_amdgcn_rcpf((1.0f + ei) * (1.0f + eg));
                    float cn  = sf * c_[u * 4 + r] + (eg - 1.0f) * rig;
                    c_[u * 4 + r] = cn;
                    float ec  = __expf(2.0f * cn);
                    float roc = __builtin_amdgcn_rcpf((1.0f + eo) * (1.0f + ec));
                    hv[q] = (ec - 1.0f) * roc;
                }
                hp[pr] = pack_bf2(hv[0], hv[1]);
            }
            uint2 hw; hw.x = hp[0]; hw.y = hp[1];
            if (t == 15) {
                *(uint2*)(Hout + (size_t)(node0 + col) * 64 + u * 16 + quad * 4) = hw;
            } else {
                int kc = u >> 1;
                int quadp = ((u & 1) << 1) + (quad >> 1);
                u16* dst = myh + (size_t)((kc * 64 + quadp * 16 + col) * 8) + (quad & 1) * 4;
                *(uint2*)dst = hw;
            }
        }
    }
}

// ---------------------------------------------------------------------------
// Fused: Y2 = relu(H@llw^T + X2@lrw^T + llb) [128]  (LDS only)
//        T1 = relu(Y2@w1^T+b1)[192]; T2 = relu(T1@w2^T+b2)[64];
//        out = relu(T2@w3^T+b3)[64] -> f32
// ---------------------------------------------------------------------------
__global__ __launch_bounds__(256) void epi_mlp_kernel(
    const u16* __restrict__ H, const u16* __restrict__ X2,       // [M,64]
    const u16* __restrict__ llw, const u16* __restrict__ llb,
    const u16* __restrict__ lrw,                                 // [128,64],[128],[128,64]
    const u16* __restrict__ w1, const u16* __restrict__ b1,      // [192,128],[192]
    const u16* __restrict__ w2, const u16* __restrict__ b2,      // [64,192],[64]
    const u16* __restrict__ w3, const u16* __restrict__ b3,      // [64,64],[64]
    float* __restrict__ out, int M)
{
    __shared__ u16 t_lds[4][16 * 192];   // 6KB/wave

    const int lane = threadIdx.x & 63;
    const int wave = threadIdx.x >> 6;
    const int row0 = (blockIdx.x * 4 + wave) * 16;
    if (row0 >= M) return;
    const int col  = lane & 15;
    const int quad = lane >> 4;
    u16* tl = t_lds[wave];

    // ---- GEMM0: Y2 (NT=8), dual K=64 ----
    f32x4 c0[8];
#pragma unroll
    for (int jt = 0; jt < 8; ++jt) c0[jt] = (f32x4){0.f, 0.f, 0.f, 0.f};
#pragma unroll
    for (int pass = 0; pass < 2; ++pass) {
        const u16* Xp = pass ? X2 : H;
        const u16* Wp = pass ? lrw : llw;
        const u16* xrow = Xp + (size_t)(row0 + col) * 64 + quad * 8;
        const u16* wrow = Wp + (size_t)col * 64 + quad * 8;
#pragma unroll
        for (int kc = 0; kc < 64; kc += 32) {
            short8 a = *(const short8*)(xrow + kc);
#pragma unroll
            for (int jt = 0; jt < 8; ++jt) {
                short8 b = *(const short8*)(wrow + (size_t)jt * 16 * 64 + kc);
                c0[jt] = __builtin_amdgcn_mfma_f32_16x16x32_bf16(a, b, c0[jt], 0, 0, 0);
            }
        }
    }
#pragma unroll
    for (int jt = 0; jt < 8; ++jt) {
        float bias = bf2f(llb[jt * 16 + col]);
#pragma unroll
        for (int r = 0; r < 4; ++r) {
            float v = fmaxf(c0[jt][r] + bias, 0.f);
            int row = quad * 4 + r;
            int k   = jt * 16 + col;
            tl[row * 128 + ((((k >> 3) ^ (row & 7))) << 3) + (k & 7)] = f2bf(v);
        }
    }
    lds_fence();

    // ---- GEMM1: T1 (NT=12), K=128, A from LDS ----
    short8 af[4];
#pragma unroll
    for (int kc = 0; kc < 4; ++kc) {
        int ch = (kc * 4 + quad) ^ (col & 7);
        af[kc] = *(const short8*)(tl + col * 128 + ch * 8);
    }
    f32x4 c1[12];
#pragma unroll
    for (int jt = 0; jt < 12; ++jt) c1[jt] = (f32x4){0.f, 0.f, 0.f, 0.f};
#pragma unroll
    for (int kc = 0; kc < 4; ++kc) {
#pragma unroll
        for (int jt = 0; jt < 12; ++jt) {
            short8 b = *(const short8*)(w1 + (size_t)(jt * 16 + col) * 128 + kc * 32 + quad * 8);
            c1[jt] = __builtin_amdgcn_mfma_f32_16x16x32_bf16(af[kc], b, c1[jt], 0, 0, 0);
        }
    }
#pragma unroll
    for (int jt = 0; jt < 12; ++jt) {
        float bias = bf2f(b1[jt * 16 + col]);
#pragma unroll
        for (int r = 0; r < 4; ++r) {
            float v = fmaxf(c1[jt][r] + bias, 0.f);
            int row = quad * 4 + r;
            int k   = jt * 16 + col;
            tl[row * 192 + ((((k >> 3) ^ (row & 7))) << 3) + (k & 7)] = f2bf(v);
        }
    }
    lds_fence();

    // ---- GEMM2: T2 (NT=4), K=192 ----
    short8 ag[6];
#pragma unroll
    for (int kc = 0; kc < 6; ++kc) {
        int ch = (kc * 4 + quad) ^ (col & 7);
        ag[kc] = *(const short8*)(tl + col * 192 + ch * 8);
    }
    f32x4 c2[4];
#pragma unroll
    for (int jt = 0; jt < 4; ++jt) c2[jt] = (f32x4){0.f, 0.f, 0.f, 0.f};
#pragma unroll
    for (int kc = 0; kc < 6; ++kc) {
#pragma unroll
        for (int jt = 0; jt < 4; ++jt) {
            short8 b = *(const short8*)(w2 + (size_t)(jt * 16 + col) * 192 + kc * 32 + quad * 8);
            c2[jt] = __builtin_amdgcn_mfma_f32_16x16x32_bf16(ag[kc], b, c2[jt], 0, 0, 0);
        }
    }
#pragma unroll
    for (int jt = 0; jt < 4; ++jt) {
        float bias = bf2f(b2[jt * 16 + col]);
#pragma unroll
        for (int r = 0; r < 4; ++r) {
            float v = fmaxf(c2[jt][r] + bias, 0.f);
            int row = quad * 4 + r;
            int k   = jt * 16 + col;
            tl[row * 64 + ((((k >> 3) ^ (row & 7))) << 3) + (k & 7)] = f2bf(v);
        }
    }
    lds_fence();

    // ---- GEMM3: out (NT=4), K=64, f32 store ----
    short8 ah[2];
#pragma unroll
    for (int kc = 0; kc < 2; ++kc) {
        int ch = (kc * 4 + quad) ^ (col & 7);
        ah[kc] = *(const short8*)(tl + col * 64 + ch * 8);
    }
    f32x4 c3[4];
#pragma unroll
    for (int jt = 0; jt < 4; ++jt) c3[jt] = (f32x4){0.f, 0.f, 0.f, 0.f};
#pragma unroll
    for (int kc = 0; kc < 2; ++kc) {
#pragma unroll
        for (int jt = 0; jt < 4; ++jt) {
            short8 b = *(const short8*)(w3 + (size_t)(jt * 16 + col) * 64 + kc * 32 + quad * 8);
            c3[jt] = __builtin_amdgcn_mfma_f32_16x16x32_bf16(ah[kc], b, c3[jt], 0, 0, 0);
        }
    }
#pragma unroll
    for (int jt = 0; jt < 4; ++jt) {
        float bias = bf2f(b3[jt * 16 + col]);
#pragma unroll
        for (int r = 0; r < 4; ++r) {
            float v = fmaxf(c3[jt][r] + bias, 0.f);
            out[(size_t)(row0 + quad * 4 + r) * 64 + jt * 16 + col] = v;
        }
    }
}

// ---------------------------------------------------------------------------
__global__ void edge_cast_kernel(const int* __restrict__ e, float* __restrict__ out, int n4)
{
    int i = blockIdx.x * blockDim.x + threadIdx.x;
    if (i < n4) {
        int4 v = *(const int4*)(e + (size_t)i * 4);
        float4 o;
        o.x = (float)v.x; o.y = (float)v.y; o.z = (float)v.z; o.w = (float)v.w;
        *(float4*)(out + (size_t)i * 4) = o;
    }
}

// ---------------------------------------------------------------------------
extern "C" void kernel_launch(void* const* d_in, const int* in_sizes, int n_in,
                              void* d_out, int out_size, void* d_ws, size_t ws_size,
                              hipStream_t stream)
{
    const u16* x       = (const u16*)d_in[0];
    const int* edge    = (const int*)d_in[1];
    const u16* p1_pw   = (const u16*)d_in[3];
    const u16* p1_pb   = (const u16*)d_in[4];
    const u16* p1_wih  = (const u16*)d_in[5];
    const u16* p1_whh  = (const u16*)d_in[6];
    const u16* p1_bih  = (const u16*)d_in[7];
    const u16* p1_bhh  = (const u16*)d_in[8];
    const u16* p1_llw  = (const u16*)d_in[9];
    const u16* p1_llb  = (const u16*)d_in[10];
    const u16* p1_lrw  = (const u16*)d_in[11];
    const u16* p2_pw   = (const u16*)d_in[12];
    const u16* p2_pb   = (const u16*)d_in[13];
    const u16* p2_wih  = (const u16*)d_in[14];
    const u16* p2_whh  = (const u16*)d_in[15];
    const u16* p2_bih  = (const u16*)d_in[16];
    const u16* p2_bhh  = (const u16*)d_in[17];
    const u16* p2_llw  = (const u16*)d_in[18];
    const u16* p2_llb  = (const u16*)d_in[19];
    const u16* p2_lrw  = (const u16*)d_in[20];
    const u16* lin1w   = (const u16*)d_in[21];
    const u16* lin1b   = (const u16*)d_in[22];
    const u16* lin2w   = (const u16*)d_in[23];
    const u16* lin2b   = (const u16*)d_in[24];
    const u16* lin3w   = (const u16*)d_in[25];
    const u16* lin3b   = (const u16*)d_in[26];
    (void)n_in; (void)ws_size;

    const int N  = in_sizes[0] / 64;     // 50000
    const int E2 = in_sizes[1];          // 1600000
    const int* srcIdx = edge;

    // workspace: G [0,26)MB, H [26,33)MB, Y1 [33,40)MB
    char* w = (char*)d_ws;
    u16* bufG  = (u16*)(w);
    u16* bufH  = (u16*)(w + 26u * 1024 * 1024);
    u16* bufY1 = (u16*)(w + 33u * 1024 * 1024);

    float* out_h    = (float*)d_out;
    float* out_edge = (float*)d_out + (size_t)N * 64;
    (void)out_size;

    {
        int n4 = E2 / 4;
        hipLaunchKernelGGL(edge_cast_kernel, dim3((n4 + 255) / 256), dim3(256), 0, stream,
                           edge, out_edge, n4);
    }

    dim3 grid((N + 63) / 64), block(256);

    // layer 1
    hipLaunchKernelGGL(proj_gates_kernel, grid, block, 0, stream,
                       x, p1_pw, p1_pb, p1_wih, p1_bih, p1_bhh, bufG, N);
    hipLaunchKernelGGL(lstm_kernel, grid, block, 0, stream, bufG, srcIdx, p1_whh, bufH, N);
    // layer-1 epilogue + layer-2 proj/gates
    hipLaunchKernelGGL(epi_pg_kernel, grid, block, 0, stream,
                       bufH, x, p1_llw, p1_llb, p1_lrw,
                       p2_pw, p2_pb, p2_wih, p2_bih, p2_bhh, bufY1, bufG, N);
    // layer 2
    hipLaunchKernelGGL(lstm_kernel, grid, block, 0, stream, bufG, srcIdx, p2_whh, bufH, N);
    // layer-2 epilogue + MLP head
    hipLaunchKernelGGL(epi_mlp_kernel, grid, block, 0, stream,
                       bufH, bufY1, p2_llw, p2_llb, p2_lrw,
                       lin1w, lin1b, lin2w, lin2b, lin3w, lin3b, out_h, N);
}

// Round 5
// 716.371 us; speedup vs baseline: 1.1535x; 1.1535x over previous
//
#include <hip/hip_runtime.h>
#include <hip/hip_bf16.h>

typedef unsigned short u16;
typedef unsigned int u32;
typedef __attribute__((ext_vector_type(8))) short short8;   // 8 bf16 (4 VGPRs) MFMA A/B frag
typedef __attribute__((ext_vector_type(4))) float f32x4;    // MFMA C/D frag

#define KS1 1.44269504f   // log2(e)
#define KS2 2.88539008f   // 2*log2(e)

__device__ __forceinline__ float bf2f(u16 u) {
    union { u32 i; float f; } v; v.i = ((u32)u) << 16; return v.f;
}
__device__ __forceinline__ u16 f2bf(float f) {            // RNE
    union { float f; u32 i; } v; v.f = f;
    u32 r = v.i + 0x7fffu + ((v.i >> 16) & 1u);
    return (u16)(r >> 16);
}
// pack two f32 -> two bf16 (truncation) in ONE v_perm
__device__ __forceinline__ u32 pack_bf2(float lo, float hi) {
    return __builtin_amdgcn_perm(__float_as_uint(hi), __float_as_uint(lo), 0x07060302u);
}
// within-wave LDS write->read fence (per-wave regions only)
__device__ __forceinline__ void lds_fence() {
    __asm__ __volatile__("s_waitcnt lgkmcnt(0)" ::: "memory");
}

// ---------------------------------------------------------------------------
// k_pre: three block roles:
//  [0, gb)            : xp1 = relu(X@pw^T + pb)  -> XP [M,64]
//  [gb, gb+eb)        : edge_index int32 -> f32 passthrough
//  [gb+eb, gb+eb+4)   : scaled weight copies (wih1,whh1,wih2,whh2) * {KS1|KS2}
// ---------------------------------------------------------------------------
__global__ __launch_bounds__(256) void k_pre(
    const u16* __restrict__ X, const u16* __restrict__ pw, const u16* __restrict__ pb,
    u16* __restrict__ XP, int M, int gb,
    const int* __restrict__ e, float* __restrict__ eout, int n4, int eb,
    const u16* __restrict__ w1i, const u16* __restrict__ w1h,
    const u16* __restrict__ w2i, const u16* __restrict__ w2h,
    u16* __restrict__ wss)
{
    const int bid = blockIdx.x;
    const int tid = threadIdx.x;
    if (bid >= gb + eb) {
        // weight scaling: matrix mi, 256x64 bf16
        int mi = bid - gb - eb;
        const u16* Wsrc = (mi == 0) ? w1i : (mi == 1) ? w1h : (mi == 2) ? w2i : w2h;
        u16* Wdst = wss + (size_t)mi * 16384;
        for (int idx = tid; idx < 16384; idx += 256) {
            int row = idx >> 6;
            float sc = (row >= 128 && row < 192) ? KS2 : KS1;
            Wdst[idx] = f2bf(bf2f(Wsrc[idx]) * sc);
        }
        return;
    }
    if (bid >= gb) {
        int i = (bid - gb) * 256 + tid;
        if (i < n4) {
            int4 v = *(const int4*)(e + (size_t)i * 4);
            float4 o;
            o.x = (float)v.x; o.y = (float)v.y; o.z = (float)v.z; o.w = (float)v.w;
            *(float4*)(eout + (size_t)i * 4) = o;
        }
        return;
    }
    // xp GEMM
    const int lane = tid & 63;
    const int wave = tid >> 6;
    const int row0 = (bid * 4 + wave) * 16;
    if (row0 >= M) return;
    const int col  = lane & 15;
    const int quad = lane >> 4;

    f32x4 c1[4];
#pragma unroll
    for (int jt = 0; jt < 4; ++jt) c1[jt] = (f32x4){0.f, 0.f, 0.f, 0.f};
    {
        const u16* xrow = X  + (size_t)(row0 + col) * 64 + quad * 8;
        const u16* wrow = pw + (size_t)col * 64 + quad * 8;
#pragma unroll
        for (int kc = 0; kc < 64; kc += 32) {
            short8 a = *(const short8*)(xrow + kc);
#pragma unroll
            for (int jt = 0; jt < 4; ++jt) {
                short8 b = *(const short8*)(wrow + (size_t)jt * 16 * 64 + kc);
                c1[jt] = __builtin_amdgcn_mfma_f32_16x16x32_bf16(a, b, c1[jt], 0, 0, 0);
            }
        }
    }
#pragma unroll
    for (int jt = 0; jt < 4; ++jt) {
        float bias = bf2f(pb[jt * 16 + col]);
#pragma unroll
        for (int r = 0; r < 4; ++r) {
            float v = fmaxf(c1[jt][r] + bias, 0.f);
            XP[(size_t)(row0 + quad * 4 + r) * 64 + jt * 16 + col] = f2bf(v);
        }
    }
}

// ---------------------------------------------------------------------------
// LSTM aggregation, lazy gates:
//   gates_t = bias' + Wih'@xp[src[n,t]] + Whh'@h_{t-1}   (all pre-scaled by
//   KS1, g-block by KS2, so exp() is bare v_exp; c kept in scaled domain)
// One wave = 16 nodes. Wih' staged in LDS (frag order, 32KB); Whh' read from
// global scaled copy (L1/L2-hot, same row pattern as tail-kernel weights).
// Gathered xp row IS the B-frag: lane(col,quad) loads xp[s_col][quad*8..] and
// [32+quad*8..] — 2x16B, zero unpack.
// NOTE: no __launch_bounds__ waves/EU cap — round 4 showed (256,3) causes
// catastrophic scratch spill (FETCH 171->664MB).
// ---------------------------------------------------------------------------
__global__ __launch_bounds__(256) void lstm_kernel(
    const u16* __restrict__ xp,    // [N,64] bf16 (unscaled)
    const int* __restrict__ src,   // [N*16]
    const u16* __restrict__ wihs,  // [256,64] scaled copy
    const u16* __restrict__ whhs,  // [256,64] scaled copy
    const u16* __restrict__ bih, const u16* __restrict__ bhh,  // [256] originals
    u16* __restrict__ Hout,        // [N,64] bf16
    int N)
{
    __shared__ u16 lds_wih[32 * 64 * 8];     // 32KB: wih frags
    __shared__ float lds_bias[256];          // 1KB: [quad][jt][r], scaled
    __shared__ u16 lds_h[4][2 * 64 * 8];     // 8KB: per-wave h frag buffer
    // 41KB total

    const int tid  = threadIdx.x;
    const int lane = tid & 63;
    const int wave = tid >> 6;
    const int col  = lane & 15;
    const int quad = lane >> 4;

    const int node0 = (blockIdx.x * 4 + wave) * 16;
    const bool active = node0 < N;   // N%16==0 -> wave-uniform

    // bias staging: thread tid handles gate j = tid
    {
        int j = tid;
        float sc = (j >= 128 && j < 192) ? KS2 : KS1;
        lds_bias[((j >> 2) & 3) * 64 + (j >> 4) * 4 + (j & 3)] =
            (bf2f(bih[j]) + bf2f(bhh[j])) * sc;
    }
    // Wih frag staging (scaled copy -> fragment order)
    for (int s = tid; s < 32 * 64; s += 256) {
        int f = s >> 6, l = s & 63;
        int jt = f >> 1, kc = f & 1;
        int row = jt * 16 + (l & 15);
        int k0  = kc * 32 + (l >> 4) * 8;
        *(short8*)(lds_wih + (size_t)s * 8) = *(const short8*)(wihs + row * 64 + k0);
    }

    const int* sp = src + (size_t)(node0 + col) * 16;
    // prefetch t=0 xp row chunks (B-frag direct)
    short8 xb0, xb1;
    {
        int s0 = active ? sp[0] : 0;
        const u16* px = xp + (size_t)s0 * 64 + quad * 8;
        xb0 = *(const short8*)px;
        xb1 = *(const short8*)(px + 32);
    }
    __syncthreads();
    if (!active) return;
    // waves independent from here (own lds_h region; lds_wih/lds_bias read-only)

    u16* myh = lds_h[wave];
    volatile const float* vb = lds_bias + quad * 64;  // volatile: prevent 64-reg hoist

    float c_[16];   // scaled-domain cell state
#pragma unroll
    for (int i = 0; i < 16; ++i) c_[i] = 0.f;

    for (int t = 0; t < 16; ++t) {
        // 1) acc init from (scaled) bias
        f32x4 acc[16];
#pragma unroll
        for (int jt = 0; jt < 16; ++jt) {
            f32x4 a;
            a[0] = vb[jt * 4 + 0]; a[1] = vb[jt * 4 + 1];
            a[2] = vb[jt * 4 + 2]; a[3] = vb[jt * 4 + 3];
            acc[jt] = a;
        }
        // 2) Wih GEMM on gathered xp (frags from LDS)
#pragma unroll
        for (int jt = 0; jt < 16; ++jt) {
            short8 a0 = *(const short8*)(lds_wih + (size_t)((jt * 2 + 0) * 64 + lane) * 8);
            acc[jt] = __builtin_amdgcn_mfma_f32_16x16x32_bf16(a0, xb0, acc[jt], 0, 0, 0);
            short8 a1 = *(const short8*)(lds_wih + (size_t)((jt * 2 + 1) * 64 + lane) * 8);
            acc[jt] = __builtin_amdgcn_mfma_f32_16x16x32_bf16(a1, xb1, acc[jt], 0, 0, 0);
        }
        // 3) prefetch next step's xp row (xb consumed above; overwrite ok)
        if (t < 15) {
            int sn = sp[t + 1];
            const u16* px = xp + (size_t)sn * 64 + quad * 8;
            xb0 = *(const short8*)px;
            xb1 = *(const short8*)(px + 32);
        }
        // 4) Whh GEMM (A-frags straight from global scaled copy; L1-hot)
        if (t > 0) {
            short8 hb0 = *(const short8*)(myh + (size_t)(0 * 64 + lane) * 8);
            short8 hb1 = *(const short8*)(myh + (size_t)(1 * 64 + lane) * 8);
#pragma unroll
            for (int jt = 0; jt < 16; ++jt) {
                const u16* wr = whhs + (size_t)(jt * 16 + col) * 64 + quad * 8;
                short8 a0 = *(const short8*)wr;
                acc[jt] = __builtin_amdgcn_mfma_f32_16x16x32_bf16(a0, hb0, acc[jt], 0, 0, 0);
                short8 a1 = *(const short8*)(wr + 32);
                acc[jt] = __builtin_amdgcn_mfma_f32_16x16x32_bf16(a1, hb1, acc[jt], 0, 0, 0);
            }
        }
        // 5) nonlinearity in scaled domain:
        //    e_i=2^-i', e_f=2^-f', e_g=2^g2'  (i'=KS1*i etc, g2'=KS2*g)
        //    c' = sig(f)*c'_prev + KS2*(e_g-1)/((1+e_i)(1+e_g))
        //    h  = (e_c-1)/((1+e_o)(1+e_c)),  e_c = 2^c' = e^{2c}
#pragma unroll
        for (int u = 0; u < 4; ++u) {
            u32 hp[2];
#pragma unroll
            for (int pr = 0; pr < 2; ++pr) {
                float hv[2];
#pragma unroll
                for (int q = 0; q < 2; ++q) {
                    int r = pr * 2 + q;
                    float iv = acc[u +  0][r];
                    float fv = acc[u +  4][r];
                    float gv = acc[u +  8][r];
                    float ov = acc[u + 12][r];
                    float e_i = __builtin_amdgcn_exp2f(-iv);
                    float e_f = __builtin_amdgcn_exp2f(-fv);
                    float e_g = __builtin_amdgcn_exp2f(gv);
                    float sf  = __builtin_amdgcn_rcpf(1.0f + e_f);
                    float rig = __builtin_amdgcn_rcpf((1.0f + e_i) * (1.0f + e_g));
                    float tt  = __builtin_fmaf(e_g, KS2, -KS2);
                    float cn  = __builtin_fmaf(sf, c_[u * 4 + r], tt * rig);
                    c_[u * 4 + r] = cn;
                    float e_c = __builtin_amdgcn_exp2f(cn);
                    float e_o = __builtin_amdgcn_exp2f(-ov);
                    float roc = __builtin_amdgcn_rcpf((1.0f + e_o) * (1.0f + e_c));
                    hv[q] = (e_c - 1.0f) * roc;
                }
                hp[pr] = pack_bf2(hv[0], hv[1]);
            }
            uint2 hw; hw.x = hp[0]; hw.y = hp[1];
            if (t == 15) {
                *(uint2*)(Hout + (size_t)(node0 + col) * 64 + u * 16 + quad * 4) = hw;
            } else {
                int kc = u >> 1;
                int quadp = ((u & 1) << 1) + (quad >> 1);
                u16* dst = myh + (size_t)((kc * 64 + quadp * 16 + col) * 8) + (quad & 1) * 4;
                *(uint2*)dst = hw;
            }
        }
    }
}

// ---------------------------------------------------------------------------
// k_mid: Y1 = relu(H@llw^T + X2@lrw^T + llb) -> global + LDS
//        xp2 = relu(Y1@pw^T + pb)            -> global
// ---------------------------------------------------------------------------
__global__ __launch_bounds__(256) void k_mid(
    const u16* __restrict__ H, const u16* __restrict__ X2,       // [M,64]
    const u16* __restrict__ llw, const u16* __restrict__ llb,
    const u16* __restrict__ lrw,
    const u16* __restrict__ pw, const u16* __restrict__ pb,
    u16* __restrict__ Y1, u16* __restrict__ XP2, int M)
{
    __shared__ u16 t_lds[4][16 * 64];

    const int lane = threadIdx.x & 63;
    const int wave = threadIdx.x >> 6;
    const int row0 = (blockIdx.x * 4 + wave) * 16;
    if (row0 >= M) return;
    const int col  = lane & 15;
    const int quad = lane >> 4;
    u16* tl = t_lds[wave];

    // GEMM0: dual K=64
    f32x4 c0[4];
#pragma unroll
    for (int jt = 0; jt < 4; ++jt) c0[jt] = (f32x4){0.f, 0.f, 0.f, 0.f};
#pragma unroll
    for (int pass = 0; pass < 2; ++pass) {
        const u16* Xp = pass ? X2 : H;
        const u16* Wp = pass ? lrw : llw;
        const u16* xrow = Xp + (size_t)(row0 + col) * 64 + quad * 8;
        const u16* wrow = Wp + (size_t)col * 64 + quad * 8;
#pragma unroll
        for (int kc = 0; kc < 64; kc += 32) {
            short8 a = *(const short8*)(xrow + kc);
#pragma unroll
            for (int jt = 0; jt < 4; ++jt) {
                short8 b = *(const short8*)(wrow + (size_t)jt * 16 * 64 + kc);
                c0[jt] = __builtin_amdgcn_mfma_f32_16x16x32_bf16(a, b, c0[jt], 0, 0, 0);
            }
        }
    }
#pragma unroll
    for (int jt = 0; jt < 4; ++jt) {
        float bias = bf2f(llb[jt * 16 + col]);
#pragma unroll
        for (int r = 0; r < 4; ++r) {
            float v = fmaxf(c0[jt][r] + bias, 0.f);
            u16 vb = f2bf(v);
            int row = quad * 4 + r;
            int k   = jt * 16 + col;
            Y1[(size_t)(row0 + row) * 64 + k] = vb;
            tl[row * 64 + ((((k >> 3) ^ (row & 7))) << 3) + (k & 7)] = vb;
        }
    }
    lds_fence();

    // GEMM1: xp2 = relu(Y1@pw^T + pb); A from LDS
    short8 a0f, a1f;
    {
        int c0i = (0 * 4 + quad) ^ (col & 7);
        int c1i = (1 * 4 + quad) ^ (col & 7);
        a0f = *(const short8*)(tl + col * 64 + c0i * 8);
        a1f = *(const short8*)(tl + col * 64 + c1i * 8);
    }
    f32x4 c1[4];
#pragma unroll
    for (int jt = 0; jt < 4; ++jt) c1[jt] = (f32x4){0.f, 0.f, 0.f, 0.f};
    {
        const u16* wrow = pw + (size_t)col * 64 + quad * 8;
#pragma unroll
        for (int jt = 0; jt < 4; ++jt) {
            short8 b0 = *(const short8*)(wrow + (size_t)jt * 16 * 64);
            c1[jt] = __builtin_amdgcn_mfma_f32_16x16x32_bf16(a0f, b0, c1[jt], 0, 0, 0);
            short8 b1 = *(const short8*)(wrow + (size_t)jt * 16 * 64 + 32);
            c1[jt] = __builtin_amdgcn_mfma_f32_16x16x32_bf16(a1f, b1, c1[jt], 0, 0, 0);
        }
    }
#pragma unroll
    for (int jt = 0; jt < 4; ++jt) {
        float bias = bf2f(pb[jt * 16 + col]);
#pragma unroll
        for (int r = 0; r < 4; ++r) {
            float v = fmaxf(c1[jt][r] + bias, 0.f);
            XP2[(size_t)(row0 + quad * 4 + r) * 64 + jt * 16 + col] = f2bf(v);
        }
    }
}

// ---------------------------------------------------------------------------
// k_post: Y2 = relu(H@llw^T + X2@lrw^T + llb) [128] (LDS only)
//         T1[192]; T2[64]; out = relu(...)[64] -> f32
// ---------------------------------------------------------------------------
__global__ __launch_bounds__(256) void k_post(
    const u16* __restrict__ H, const u16* __restrict__ X2,
    const u16* __restrict__ llw, const u16* __restrict__ llb,
    const u16* __restrict__ lrw,
    const u16* __restrict__ w1, const u16* __restrict__ b1,
    const u16* __restrict__ w2, const u16* __restrict__ b2,
    const u16* __restrict__ w3, const u16* __restrict__ b3,
    float* __restrict__ out, int M)
{
    __shared__ u16 t_lds[4][16 * 192];

    const int lane = threadIdx.x & 63;
    const int wave = threadIdx.x >> 6;
    const int row0 = (blockIdx.x * 4 + wave) * 16;
    if (row0 >= M) return;
    const int col  = lane & 15;
    const int quad = lane >> 4;
    u16* tl = t_lds[wave];

    // GEMM0: Y2 (NT=8), dual K=64
    f32x4 c0[8];
#pragma unroll
    for (int jt = 0; jt < 8; ++jt) c0[jt] = (f32x4){0.f, 0.f, 0.f, 0.f};
#pragma unroll
    for (int pass = 0; pass < 2; ++pass) {
        const u16* Xp = pass ? X2 : H;
        const u16* Wp = pass ? lrw : llw;
        const u16* xrow = Xp + (size_t)(row0 + col) * 64 + quad * 8;
        const u16* wrow = Wp + (size_t)col * 64 + quad * 8;
#pragma unroll
        for (int kc = 0; kc < 64; kc += 32) {
            short8 a = *(const short8*)(xrow + kc);
#pragma unroll
            for (int jt = 0; jt < 8; ++jt) {
                short8 b = *(const short8*)(wrow + (size_t)jt * 16 * 64 + kc);
                c0[jt] = __builtin_amdgcn_mfma_f32_16x16x32_bf16(a, b, c0[jt], 0, 0, 0);
            }
        }
    }
#pragma unroll
    for (int jt = 0; jt < 8; ++jt) {
        float bias = bf2f(llb[jt * 16 + col]);
#pragma unroll
        for (int r = 0; r < 4; ++r) {
            float v = fmaxf(c0[jt][r] + bias, 0.f);
            int row = quad * 4 + r;
            int k   = jt * 16 + col;
            tl[row * 128 + ((((k >> 3) ^ (row & 7))) << 3) + (k & 7)] = f2bf(v);
        }
    }
    lds_fence();

    // GEMM1: T1 (NT=12), K=128
    short8 af[4];
#pragma unroll
    for (int kc = 0; kc < 4; ++kc) {
        int ch = (kc * 4 + quad) ^ (col & 7);
        af[kc] = *(const short8*)(tl + col * 128 + ch * 8);
    }
    f32x4 c1[12];
#pragma unroll
    for (int jt = 0; jt < 12; ++jt) c1[jt] = (f32x4){0.f, 0.f, 0.f, 0.f};
#pragma unroll
    for (int kc = 0; kc < 4; ++kc) {
#pragma unroll
        for (int jt = 0; jt < 12; ++jt) {
            short8 b = *(const short8*)(w1 + (size_t)(jt * 16 + col) * 128 + kc * 32 + quad * 8);
            c1[jt] = __builtin_amdgcn_mfma_f32_16x16x32_bf16(af[kc], b, c1[jt], 0, 0, 0);
        }
    }
#pragma unroll
    for (int jt = 0; jt < 12; ++jt) {
        float bias = bf2f(b1[jt * 16 + col]);
#pragma unroll
        for (int r = 0; r < 4; ++r) {
            float v = fmaxf(c1[jt][r] + bias, 0.f);
            int row = quad * 4 + r;
            int k   = jt * 16 + col;
            tl[row * 192 + ((((k >> 3) ^ (row & 7))) << 3) + (k & 7)] = f2bf(v);
        }
    }
    lds_fence();

    // GEMM2: T2 (NT=4), K=192
    short8 ag[6];
#pragma unroll
    for (int kc = 0; kc < 6; ++kc) {
        int ch = (kc * 4 + quad) ^ (col & 7);
        ag[kc] = *(const short8*)(tl + col * 192 + ch * 8);
    }
    f32x4 c2[4];
#pragma unroll
    for (int jt = 0; jt < 4; ++jt) c2[jt] = (f32x4){0.f, 0.f, 0.f, 0.f};
#pragma unroll
    for (int kc = 0; kc < 6; ++kc) {
#pragma unroll
        for (int jt = 0; jt < 4; ++jt) {
            short8 b = *(const short8*)(w2 + (size_t)(jt * 16 + col) * 192 + kc * 32 + quad * 8);
            c2[jt] = __builtin_amdgcn_mfma_f32_16x16x32_bf16(ag[kc], b, c2[jt], 0, 0, 0);
        }
    }
#pragma unroll
    for (int jt = 0; jt < 4; ++jt) {
        float bias = bf2f(b2[jt * 16 + col]);
#pragma unroll
        for (int r = 0; r < 4; ++r) {
            float v = fmaxf(c2[jt][r] + bias, 0.f);
            int row = quad * 4 + r;
            int k   = jt * 16 + col;
            tl[row * 64 + ((((k >> 3) ^ (row & 7))) << 3) + (k & 7)] = f2bf(v);
        }
    }
    lds_fence();

    // GEMM3: out (NT=4), K=64, f32 store
    short8 ah[2];
#pragma unroll
    for (int kc = 0; kc < 2; ++kc) {
        int ch = (kc * 4 + quad) ^ (col & 7);
        ah[kc] = *(const short8*)(tl + col * 64 + ch * 8);
    }
    f32x4 c3[4];
#pragma unroll
    for (int jt = 0; jt < 4; ++jt) c3[jt] = (f32x4){0.f, 0.f, 0.f, 0.f};
#pragma unroll
    for (int kc = 0; kc < 2; ++kc) {
#pragma unroll
        for (int jt = 0; jt < 4; ++jt) {
            short8 b = *(const short8*)(w3 + (size_t)(jt * 16 + col) * 64 + kc * 32 + quad * 8);
            c3[jt] = __builtin_amdgcn_mfma_f32_16x16x32_bf16(ah[kc], b, c3[jt], 0, 0, 0);
        }
    }
#pragma unroll
    for (int jt = 0; jt < 4; ++jt) {
        float bias = bf2f(b3[jt * 16 + col]);
#pragma unroll
        for (int r = 0; r < 4; ++r) {
            float v = fmaxf(c3[jt][r] + bias, 0.f);
            out[(size_t)(row0 + quad * 4 + r) * 64 + jt * 16 + col] = v;
        }
    }
}

// ---------------------------------------------------------------------------
extern "C" void kernel_launch(void* const* d_in, const int* in_sizes, int n_in,
                              void* d_out, int out_size, void* d_ws, size_t ws_size,
                              hipStream_t stream)
{
    const u16* x       = (const u16*)d_in[0];
    const int* edge    = (const int*)d_in[1];
    const u16* p1_pw   = (const u16*)d_in[3];
    const u16* p1_pb   = (const u16*)d_in[4];
    const u16* p1_wih  = (const u16*)d_in[5];
    const u16* p1_whh  = (const u16*)d_in[6];
    const u16* p1_bih  = (const u16*)d_in[7];
    const u16* p1_bhh  = (const u16*)d_in[8];
    const u16* p1_llw  = (const u16*)d_in[9];
    const u16* p1_llb  = (const u16*)d_in[10];
    const u16* p1_lrw  = (const u16*)d_in[11];
    const u16* p2_pw   = (const u16*)d_in[12];
    const u16* p2_pb   = (const u16*)d_in[13];
    const u16* p2_wih  = (const u16*)d_in[14];
    const u16* p2_whh  = (const u16*)d_in[15];
    const u16* p2_bih  = (const u16*)d_in[16];
    const u16* p2_bhh  = (const u16*)d_in[17];
    const u16* p2_llw  = (const u16*)d_in[18];
    const u16* p2_llb  = (const u16*)d_in[19];
    const u16* p2_lrw  = (const u16*)d_in[20];
    const u16* lin1w   = (const u16*)d_in[21];
    const u16* lin1b   = (const u16*)d_in[22];
    const u16* lin2w   = (const u16*)d_in[23];
    const u16* lin2b   = (const u16*)d_in[24];
    const u16* lin3w   = (const u16*)d_in[25];
    const u16* lin3b   = (const u16*)d_in[26];
    (void)n_in; (void)ws_size;

    const int N  = in_sizes[0] / 64;     // 50000
    const int E2 = in_sizes[1];          // 1600000
    const int* srcIdx = edge;

    // workspace: scaled weights 128KB @0; xp1 @1MB; H @8MB; Y1 @15MB; xp2 @22MB
    char* w = (char*)d_ws;
    u16* wss   = (u16*)(w);
    u16* xp1   = (u16*)(w + 1u  * 1024 * 1024);
    u16* bufH  = (u16*)(w + 8u  * 1024 * 1024);
    u16* bufY1 = (u16*)(w + 15u * 1024 * 1024);
    u16* xp2   = (u16*)(w + 22u * 1024 * 1024);
    u16* wih1s = wss;
    u16* whh1s = wss + 16384;
    u16* wih2s = wss + 32768;
    u16* whh2s = wss + 49152;

    float* out_h    = (float*)d_out;
    float* out_edge = (float*)d_out + (size_t)N * 64;
    (void)out_size;

    const int gb = (N + 63) / 64;        // 782
    const int n4 = E2 / 4;
    const int eb = (n4 + 255) / 256;     // 1563

    dim3 block(256);

    // k_pre: xp1 + edge cast + weight scaling
    hipLaunchKernelGGL(k_pre, dim3(gb + eb + 4), block, 0, stream,
                       x, p1_pw, p1_pb, xp1, N, gb,
                       edge, out_edge, n4, eb,
                       p1_wih, p1_whh, p2_wih, p2_whh, wss);
    // layer 1 LSTM
    hipLaunchKernelGGL(lstm_kernel, dim3(gb), block, 0, stream,
                       xp1, srcIdx, wih1s, whh1s, p1_bih, p1_bhh, bufH, N);
    // layer-1 epilogue + layer-2 projection
    hipLaunchKernelGGL(k_mid, dim3(gb), block, 0, stream,
                       bufH, x, p1_llw, p1_llb, p1_lrw, p2_pw, p2_pb, bufY1, xp2, N);
    // layer 2 LSTM
    hipLaunchKernelGGL(lstm_kernel, dim3(gb), block, 0, stream,
                       xp2, srcIdx, wih2s, whh2s, p2_bih, p2_bhh, bufH, N);
    // layer-2 epilogue + MLP head
    hipLaunchKernelGGL(k_post, dim3(gb), block, 0, stream,
                       bufH, bufY1, p2_llw, p2_llb, p2_lrw,
                       lin1w, lin1b, lin2w, lin2b, lin3w, lin3b, out_h, N);
}

// Round 6
// 483.541 us; speedup vs baseline: 1.7089x; 1.4815x over previous
//
#include <hip/hip_runtime.h>
#include <hip/hip_bf16.h>

typedef unsigned short u16;
typedef unsigned int u32;
typedef __attribute__((ext_vector_type(8))) short short8;   // 8 bf16 (4 VGPRs) MFMA A/B frag
typedef __attribute__((ext_vector_type(4))) float f32x4;    // MFMA C/D frag

#define KS1 1.44269504f   // log2(e)
#define KS2 2.88539008f   // 2*log2(e)

__device__ __forceinline__ float bf2f(u16 u) {
    union { u32 i; float f; } v; v.i = ((u32)u) << 16; return v.f;
}
__device__ __forceinline__ u16 f2bf(float f) {            // RNE
    union { float f; u32 i; } v; v.f = f;
    u32 r = v.i + 0x7fffu + ((v.i >> 16) & 1u);
    return (u16)(r >> 16);
}
// pack two f32 -> two bf16 (truncation) in ONE v_perm
__device__ __forceinline__ u32 pack_bf2(float lo, float hi) {
    return __builtin_amdgcn_perm(__float_as_uint(hi), __float_as_uint(lo), 0x07060302u);
}
// within-wave LDS write->read fence (per-wave regions only)
__device__ __forceinline__ void lds_fence() {
    __asm__ __volatile__("s_waitcnt lgkmcnt(0)" ::: "memory");
}

// ---------------------------------------------------------------------------
// k_pre: three block roles:
//  [0, gb)            : xp1 = relu(X@pw^T + pb)  -> XP [M,64]
//  [gb, gb+eb)        : edge_index int32 -> f32 passthrough
//  [gb+eb, gb+eb+4)   : scaled weight copies (wih1,whh1,wih2,whh2) * {KS1|KS2}
// ---------------------------------------------------------------------------
__global__ __launch_bounds__(256) void k_pre(
    const u16* __restrict__ X, const u16* __restrict__ pw, const u16* __restrict__ pb,
    u16* __restrict__ XP, int M, int gb,
    const int* __restrict__ e, float* __restrict__ eout, int n4, int eb,
    const u16* __restrict__ w1i, const u16* __restrict__ w1h,
    const u16* __restrict__ w2i, const u16* __restrict__ w2h,
    u16* __restrict__ wss)
{
    const int bid = blockIdx.x;
    const int tid = threadIdx.x;
    if (bid >= gb + eb) {
        int mi = bid - gb - eb;
        const u16* Wsrc = (mi == 0) ? w1i : (mi == 1) ? w1h : (mi == 2) ? w2i : w2h;
        u16* Wdst = wss + (size_t)mi * 16384;
        for (int idx = tid; idx < 16384; idx += 256) {
            int row = idx >> 6;
            float sc = (row >= 128 && row < 192) ? KS2 : KS1;
            Wdst[idx] = f2bf(bf2f(Wsrc[idx]) * sc);
        }
        return;
    }
    if (bid >= gb) {
        int i = (bid - gb) * 256 + tid;
        if (i < n4) {
            int4 v = *(const int4*)(e + (size_t)i * 4);
            float4 o;
            o.x = (float)v.x; o.y = (float)v.y; o.z = (float)v.z; o.w = (float)v.w;
            *(float4*)(eout + (size_t)i * 4) = o;
        }
        return;
    }
    const int lane = tid & 63;
    const int wave = tid >> 6;
    const int row0 = (bid * 4 + wave) * 16;
    if (row0 >= M) return;
    const int col  = lane & 15;
    const int quad = lane >> 4;

    f32x4 c1[4];
#pragma unroll
    for (int jt = 0; jt < 4; ++jt) c1[jt] = (f32x4){0.f, 0.f, 0.f, 0.f};
    {
        const u16* xrow = X  + (size_t)(row0 + col) * 64 + quad * 8;
        const u16* wrow = pw + (size_t)col * 64 + quad * 8;
#pragma unroll
        for (int kc = 0; kc < 64; kc += 32) {
            short8 a = *(const short8*)(xrow + kc);
#pragma unroll
            for (int jt = 0; jt < 4; ++jt) {
                short8 b = *(const short8*)(wrow + (size_t)jt * 16 * 64 + kc);
                c1[jt] = __builtin_amdgcn_mfma_f32_16x16x32_bf16(a, b, c1[jt], 0, 0, 0);
            }
        }
    }
#pragma unroll
    for (int jt = 0; jt < 4; ++jt) {
        float bias = bf2f(pb[jt * 16 + col]);
#pragma unroll
        for (int r = 0; r < 4; ++r) {
            float v = fmaxf(c1[jt][r] + bias, 0.f);
            XP[(size_t)(row0 + quad * 4 + r) * 64 + jt * 16 + col] = f2bf(v);
        }
    }
}

// ---------------------------------------------------------------------------
// LSTM aggregation, lazy gates, v2:
//   gates_t = bias' (C-operand regs) + Wih'@xp[src] + Whh'@h   (scaled domain)
// - Wih'+Whh' both in LDS (64KB, fragment order) — no per-step global weight
//   loads (round 5's L1-latency chain), no LDS h buffer, no LDS bias.
// - bias': 16 f32x4 persistent VGPRs, consumed as the C operand of the first
//   MFMA per jt (D != C, so zero per-step cost).
// - h C-layout -> next-step B-frag via ds_bpermute (crossbar, no banks).
// - xp gather prefetched one step ahead (row IS the B-frag, zero unpack).
// NOTE: no waves/EU cap (round 4: (256,3) => catastrophic scratch spill).
// ---------------------------------------------------------------------------
__global__ __launch_bounds__(256) void lstm_kernel(
    const u16* __restrict__ xp,    // [N,64] bf16 (unscaled)
    const int* __restrict__ src,   // [N*16]
    const u16* __restrict__ wihs,  // [256,64] scaled copy
    const u16* __restrict__ whhs,  // [256,64] scaled copy
    const u16* __restrict__ bih, const u16* __restrict__ bhh,  // [256] originals
    u16* __restrict__ Hout,        // [N,64] bf16
    int N)
{
    __shared__ u16 lds_w[32768];   // 64KB: wih frags @0, whh frags @16384 (u16)

    const int tid  = threadIdx.x;
    const int lane = tid & 63;
    const int wave = tid >> 6;
    const int col  = lane & 15;
    const int quad = lane >> 4;

    const int node0 = (blockIdx.x * 4 + wave) * 16;
    const bool active = node0 < N;   // N%16==0 -> wave-uniform

    // ---- persistent bias C-operands (scaled): bias_c[jt][r] = (bih+bhh)[jt*16+quad*4+r]*sc
    f32x4 bias_c[16];
#pragma unroll
    for (int jt = 0; jt < 16; ++jt) {
        uint2 u1 = *(const uint2*)(bih + jt * 16 + quad * 4);
        uint2 u2 = *(const uint2*)(bhh + jt * 16 + quad * 4);
        float sc = (jt >= 8 && jt < 12) ? KS2 : KS1;
        bias_c[jt][0] = (bf2f((u16)(u1.x & 0xffffu)) + bf2f((u16)(u2.x & 0xffffu))) * sc;
        bias_c[jt][1] = (bf2f((u16)(u1.x >> 16))     + bf2f((u16)(u2.x >> 16)))     * sc;
        bias_c[jt][2] = (bf2f((u16)(u1.y & 0xffffu)) + bf2f((u16)(u2.y & 0xffffu))) * sc;
        bias_c[jt][3] = (bf2f((u16)(u1.y >> 16))     + bf2f((u16)(u2.y >> 16)))     * sc;
    }

    // ---- stage Wih' and Whh' into LDS in fragment order
    for (int s = tid; s < 4096; s += 256) {
        int tbl = s >> 11;                    // 0: wih, 1: whh
        int f = (s >> 6) & 31, l = s & 63;
        int jt = f >> 1, kc = f & 1;
        const u16* W = tbl ? whhs : wihs;
        int row = jt * 16 + (l & 15);
        int k0  = kc * 32 + (l >> 4) * 8;
        *(short8*)(lds_w + (size_t)s * 8) = *(const short8*)(W + row * 64 + k0);
    }

    const int* sp = src + (size_t)(node0 + col) * 16;
    // prefetch t=0 xp row chunks (B-frag direct)
    short8 xb0, xb1;
    {
        int s0 = active ? sp[0] : 0;
        const u16* px = xp + (size_t)s0 * 64 + quad * 8;
        xb0 = *(const short8*)px;
        xb1 = *(const short8*)(px + 32);
    }
    __syncthreads();
    if (!active) return;
    // waves fully independent from here (lds_w read-only; no more barriers)

    // bpermute byte-indices for the h exchange
    const int idxA = (((quad & 1) * 32) + col) * 4;   // w in {0,1}
    const int idxB = idxA + 64;                       // w in {2,3}

    short8 hb0 = (short8){0,0,0,0,0,0,0,0};
    short8 hb1 = (short8){0,0,0,0,0,0,0,0};

    float c_[16];   // scaled-domain cell state
#pragma unroll
    for (int i = 0; i < 16; ++i) c_[i] = 0.f;

#pragma unroll 1
    for (int t = 0; t < 16; ++t) {
        // 1) Wih GEMM on gathered xp; bias enters as the C operand (free)
        f32x4 acc[16];
#pragma unroll
        for (int jt = 0; jt < 16; ++jt) {
            short8 a0 = *(const short8*)(lds_w + (size_t)((jt * 2 + 0) * 64 + lane) * 8);
            acc[jt] = __builtin_amdgcn_mfma_f32_16x16x32_bf16(a0, xb0, bias_c[jt], 0, 0, 0);
            short8 a1 = *(const short8*)(lds_w + (size_t)((jt * 2 + 1) * 64 + lane) * 8);
            acc[jt] = __builtin_amdgcn_mfma_f32_16x16x32_bf16(a1, xb1, acc[jt], 0, 0, 0);
        }
        // 2) prefetch next step's xp row (xb consumed above)
        if (t < 15) {
            int sn = sp[t + 1];
            const u16* px = xp + (size_t)sn * 64 + quad * 8;
            xb0 = *(const short8*)px;
            xb1 = *(const short8*)(px + 32);
        }
        // 3) Whh GEMM (frags from LDS)
        if (t > 0) {
#pragma unroll
            for (int jt = 0; jt < 16; ++jt) {
                short8 a0 = *(const short8*)(lds_w + 16384 + (size_t)((jt * 2 + 0) * 64 + lane) * 8);
                acc[jt] = __builtin_amdgcn_mfma_f32_16x16x32_bf16(a0, hb0, acc[jt], 0, 0, 0);
                short8 a1 = *(const short8*)(lds_w + 16384 + (size_t)((jt * 2 + 1) * 64 + lane) * 8);
                acc[jt] = __builtin_amdgcn_mfma_f32_16x16x32_bf16(a1, hb1, acc[jt], 0, 0, 0);
            }
        }
        // 4) nonlinearity in scaled domain (c' = 2log2e * c)
        u32 hword[8];   // C-layout h words: hword[u*2+p] = dims u*16+quad*4+2p+{0,1}
#pragma unroll
        for (int u = 0; u < 4; ++u) {
            u32 hp[2];
#pragma unroll
            for (int pr = 0; pr < 2; ++pr) {
                float hv[2];
#pragma unroll
                for (int q = 0; q < 2; ++q) {
                    int r = pr * 2 + q;
                    float iv = acc[u +  0][r];
                    float fv = acc[u +  4][r];
                    float gv = acc[u +  8][r];
                    float ov = acc[u + 12][r];
                    float e_i = __builtin_amdgcn_exp2f(-iv);
                    float e_f = __builtin_amdgcn_exp2f(-fv);
                    float e_g = __builtin_amdgcn_exp2f(gv);
                    float sf  = __builtin_amdgcn_rcpf(1.0f + e_f);
                    float rig = __builtin_amdgcn_rcpf((1.0f + e_i) * (1.0f + e_g));
                    float tt  = __builtin_fmaf(e_g, KS2, -KS2);
                    float cn  = __builtin_fmaf(sf, c_[u * 4 + r], tt * rig);
                    c_[u * 4 + r] = cn;
                    float e_c = __builtin_amdgcn_exp2f(cn);
                    float e_o = __builtin_amdgcn_exp2f(-ov);
                    float roc = __builtin_amdgcn_rcpf((1.0f + e_o) * (1.0f + e_c));
                    hv[q] = (e_c - 1.0f) * roc;
                }
                hp[pr] = pack_bf2(hv[0], hv[1]);
            }
            hword[u * 2 + 0] = hp[0];
            hword[u * 2 + 1] = hp[1];
            if (t == 15) {
                uint2 hw; hw.x = hp[0]; hw.y = hp[1];
                *(uint2*)(Hout + (size_t)(node0 + col) * 64 + u * 16 + quad * 4) = hw;
            }
        }
        // 5) C-layout -> B-frag h exchange via ds_bpermute (no LDS storage)
        //    target word (f,w): src word f*4 + (quad>>1)*2 + (w&1),
        //    src lane ((quad&1)*2 + (w>>1))*16 + col
        if (t < 15) {
            union { u32 w[4]; short8 v; } x0, x1;
#pragma unroll
            for (int w = 0; w < 4; ++w) {
                int idx = (w < 2) ? idxA : idxB;
                u32 lo0 = (u32)__builtin_amdgcn_ds_bpermute(idx, (int)hword[0 + (w & 1)]);
                u32 hi0 = (u32)__builtin_amdgcn_ds_bpermute(idx, (int)hword[2 + (w & 1)]);
                x0.w[w] = (quad < 2) ? lo0 : hi0;
                u32 lo1 = (u32)__builtin_amdgcn_ds_bpermute(idx, (int)hword[4 + (w & 1)]);
                u32 hi1 = (u32)__builtin_amdgcn_ds_bpermute(idx, (int)hword[6 + (w & 1)]);
                x1.w[w] = (quad < 2) ? lo1 : hi1;
            }
            hb0 = x0.v;
            hb1 = x1.v;
        }
    }
}

// ---------------------------------------------------------------------------
// k_mid: Y1 = relu(H@llw^T + X2@lrw^T + llb) -> global + LDS
//        xp2 = relu(Y1@pw^T + pb)            -> global
// ---------------------------------------------------------------------------
__global__ __launch_bounds__(256) void k_mid(
    const u16* __restrict__ H, const u16* __restrict__ X2,       // [M,64]
    const u16* __restrict__ llw, const u16* __restrict__ llb,
    const u16* __restrict__ lrw,
    const u16* __restrict__ pw, const u16* __restrict__ pb,
    u16* __restrict__ Y1, u16* __restrict__ XP2, int M)
{
    __shared__ u16 t_lds[4][16 * 64];

    const int lane = threadIdx.x & 63;
    const int wave = threadIdx.x >> 6;
    const int row0 = (blockIdx.x * 4 + wave) * 16;
    if (row0 >= M) return;
    const int col  = lane & 15;
    const int quad = lane >> 4;
    u16* tl = t_lds[wave];

    f32x4 c0[4];
#pragma unroll
    for (int jt = 0; jt < 4; ++jt) c0[jt] = (f32x4){0.f, 0.f, 0.f, 0.f};
#pragma unroll
    for (int pass = 0; pass < 2; ++pass) {
        const u16* Xp = pass ? X2 : H;
        const u16* Wp = pass ? lrw : llw;
        const u16* xrow = Xp + (size_t)(row0 + col) * 64 + quad * 8;
        const u16* wrow = Wp + (size_t)col * 64 + quad * 8;
#pragma unroll
        for (int kc = 0; kc < 64; kc += 32) {
            short8 a = *(const short8*)(xrow + kc);
#pragma unroll
            for (int jt = 0; jt < 4; ++jt) {
                short8 b = *(const short8*)(wrow + (size_t)jt * 16 * 64 + kc);
                c0[jt] = __builtin_amdgcn_mfma_f32_16x16x32_bf16(a, b, c0[jt], 0, 0, 0);
            }
        }
    }
#pragma unroll
    for (int jt = 0; jt < 4; ++jt) {
        float bias = bf2f(llb[jt * 16 + col]);
#pragma unroll
        for (int r = 0; r < 4; ++r) {
            float v = fmaxf(c0[jt][r] + bias, 0.f);
            u16 vb = f2bf(v);
            int row = quad * 4 + r;
            int k   = jt * 16 + col;
            Y1[(size_t)(row0 + row) * 64 + k] = vb;
            tl[row * 64 + ((((k >> 3) ^ (row & 7))) << 3) + (k & 7)] = vb;
        }
    }
    lds_fence();

    short8 a0f, a1f;
    {
        int c0i = (0 * 4 + quad) ^ (col & 7);
        int c1i = (1 * 4 + quad) ^ (col & 7);
        a0f = *(const short8*)(tl + col * 64 + c0i * 8);
        a1f = *(const short8*)(tl + col * 64 + c1i * 8);
    }
    f32x4 c1[4];
#pragma unroll
    for (int jt = 0; jt < 4; ++jt) c1[jt] = (f32x4){0.f, 0.f, 0.f, 0.f};
    {
        const u16* wrow = pw + (size_t)col * 64 + quad * 8;
#pragma unroll
        for (int jt = 0; jt < 4; ++jt) {
            short8 b0 = *(const short8*)(wrow + (size_t)jt * 16 * 64);
            c1[jt] = __builtin_amdgcn_mfma_f32_16x16x32_bf16(a0f, b0, c1[jt], 0, 0, 0);
            short8 b1 = *(const short8*)(wrow + (size_t)jt * 16 * 64 + 32);
            c1[jt] = __builtin_amdgcn_mfma_f32_16x16x32_bf16(a1f, b1, c1[jt], 0, 0, 0);
        }
    }
#pragma unroll
    for (int jt = 0; jt < 4; ++jt) {
        float bias = bf2f(pb[jt * 16 + col]);
#pragma unroll
        for (int r = 0; r < 4; ++r) {
            float v = fmaxf(c1[jt][r] + bias, 0.f);
            XP2[(size_t)(row0 + quad * 4 + r) * 64 + jt * 16 + col] = f2bf(v);
        }
    }
}

// ---------------------------------------------------------------------------
// k_post: Y2 = relu(H@llw^T + X2@lrw^T + llb) [128] (LDS only)
//         T1[192]; T2[64]; out = relu(...)[64] -> f32
// ---------------------------------------------------------------------------
__global__ __launch_bounds__(256) void k_post(
    const u16* __restrict__ H, const u16* __restrict__ X2,
    const u16* __restrict__ llw, const u16* __restrict__ llb,
    const u16* __restrict__ lrw,
    const u16* __restrict__ w1, const u16* __restrict__ b1,
    const u16* __restrict__ w2, const u16* __restrict__ b2,
    const u16* __restrict__ w3, const u16* __restrict__ b3,
    float* __restrict__ out, int M)
{
    __shared__ u16 t_lds[4][16 * 192];

    const int lane = threadIdx.x & 63;
    const int wave = threadIdx.x >> 6;
    const int row0 = (blockIdx.x * 4 + wave) * 16;
    if (row0 >= M) return;
    const int col  = lane & 15;
    const int quad = lane >> 4;
    u16* tl = t_lds[wave];

    f32x4 c0[8];
#pragma unroll
    for (int jt = 0; jt < 8; ++jt) c0[jt] = (f32x4){0.f, 0.f, 0.f, 0.f};
#pragma unroll
    for (int pass = 0; pass < 2; ++pass) {
        const u16* Xp = pass ? X2 : H;
        const u16* Wp = pass ? lrw : llw;
        const u16* xrow = Xp + (size_t)(row0 + col) * 64 + quad * 8;
        const u16* wrow = Wp + (size_t)col * 64 + quad * 8;
#pragma unroll
        for (int kc = 0; kc < 64; kc += 32) {
            short8 a = *(const short8*)(xrow + kc);
#pragma unroll
            for (int jt = 0; jt < 8; ++jt) {
                short8 b = *(const short8*)(wrow + (size_t)jt * 16 * 64 + kc);
                c0[jt] = __builtin_amdgcn_mfma_f32_16x16x32_bf16(a, b, c0[jt], 0, 0, 0);
            }
        }
    }
#pragma unroll
    for (int jt = 0; jt < 8; ++jt) {
        float bias = bf2f(llb[jt * 16 + col]);
#pragma unroll
        for (int r = 0; r < 4; ++r) {
            float v = fmaxf(c0[jt][r] + bias, 0.f);
            int row = quad * 4 + r;
            int k   = jt * 16 + col;
            tl[row * 128 + ((((k >> 3) ^ (row & 7))) << 3) + (k & 7)] = f2bf(v);
        }
    }
    lds_fence();

    short8 af[4];
#pragma unroll
    for (int kc = 0; kc < 4; ++kc) {
        int ch = (kc * 4 + quad) ^ (col & 7);
        af[kc] = *(const short8*)(tl + col * 128 + ch * 8);
    }
    f32x4 c1[12];
#pragma unroll
    for (int jt = 0; jt < 12; ++jt) c1[jt] = (f32x4){0.f, 0.f, 0.f, 0.f};
#pragma unroll
    for (int kc = 0; kc < 4; ++kc) {
#pragma unroll
        for (int jt = 0; jt < 12; ++jt) {
            short8 b = *(const short8*)(w1 + (size_t)(jt * 16 + col) * 128 + kc * 32 + quad * 8);
            c1[jt] = __builtin_amdgcn_mfma_f32_16x16x32_bf16(af[kc], b, c1[jt], 0, 0, 0);
        }
    }
#pragma unroll
    for (int jt = 0; jt < 12; ++jt) {
        float bias = bf2f(b1[jt * 16 + col]);
#pragma unroll
        for (int r = 0; r < 4; ++r) {
            float v = fmaxf(c1[jt][r] + bias, 0.f);
            int row = quad * 4 + r;
            int k   = jt * 16 + col;
            tl[row * 192 + ((((k >> 3) ^ (row & 7))) << 3) + (k & 7)] = f2bf(v);
        }
    }
    lds_fence();

    short8 ag[6];
#pragma unroll
    for (int kc = 0; kc < 6; ++kc) {
        int ch = (kc * 4 + quad) ^ (col & 7);
        ag[kc] = *(const short8*)(tl + col * 192 + ch * 8);
    }
    f32x4 c2[4];
#pragma unroll
    for (int jt = 0; jt < 4; ++jt) c2[jt] = (f32x4){0.f, 0.f, 0.f, 0.f};
#pragma unroll
    for (int kc = 0; kc < 6; ++kc) {
#pragma unroll
        for (int jt = 0; jt < 4; ++jt) {
            short8 b = *(const short8*)(w2 + (size_t)(jt * 16 + col) * 192 + kc * 32 + quad * 8);
            c2[jt] = __builtin_amdgcn_mfma_f32_16x16x32_bf16(ag[kc], b, c2[jt], 0, 0, 0);
        }
    }
#pragma unroll
    for (int jt = 0; jt < 4; ++jt) {
        float bias = bf2f(b2[jt * 16 + col]);
#pragma unroll
        for (int r = 0; r < 4; ++r) {
            float v = fmaxf(c2[jt][r] + bias, 0.f);
            int row = quad * 4 + r;
            int k   = jt * 16 + col;
            tl[row * 64 + ((((k >> 3) ^ (row & 7))) << 3) + (k & 7)] = f2bf(v);
        }
    }
    lds_fence();

    short8 ah[2];
#pragma unroll
    for (int kc = 0; kc < 2; ++kc) {
        int ch = (kc * 4 + quad) ^ (col & 7);
        ah[kc] = *(const short8*)(tl + col * 64 + ch * 8);
    }
    f32x4 c3[4];
#pragma unroll
    for (int jt = 0; jt < 4; ++jt) c3[jt] = (f32x4){0.f, 0.f, 0.f, 0.f};
#pragma unroll
    for (int kc = 0; kc < 2; ++kc) {
#pragma unroll
        for (int jt = 0; jt < 4; ++jt) {
            short8 b = *(const short8*)(w3 + (size_t)(jt * 16 + col) * 64 + kc * 32 + quad * 8);
            c3[jt] = __builtin_amdgcn_mfma_f32_16x16x32_bf16(ah[kc], b, c3[jt], 0, 0, 0);
        }
    }
#pragma unroll
    for (int jt = 0; jt < 4; ++jt) {
        float bias = bf2f(b3[jt * 16 + col]);
#pragma unroll
        for (int r = 0; r < 4; ++r) {
            float v = fmaxf(c3[jt][r] + bias, 0.f);
            out[(size_t)(row0 + quad * 4 + r) * 64 + jt * 16 + col] = v;
        }
    }
}

// ---------------------------------------------------------------------------
extern "C" void kernel_launch(void* const* d_in, const int* in_sizes, int n_in,
                              void* d_out, int out_size, void* d_ws, size_t ws_size,
                              hipStream_t stream)
{
    const u16* x       = (const u16*)d_in[0];
    const int* edge    = (const int*)d_in[1];
    const u16* p1_pw   = (const u16*)d_in[3];
    const u16* p1_pb   = (const u16*)d_in[4];
    const u16* p1_wih  = (const u16*)d_in[5];
    const u16* p1_whh  = (const u16*)d_in[6];
    const u16* p1_bih  = (const u16*)d_in[7];
    const u16* p1_bhh  = (const u16*)d_in[8];
    const u16* p1_llw  = (const u16*)d_in[9];
    const u16* p1_llb  = (const u16*)d_in[10];
    const u16* p1_lrw  = (const u16*)d_in[11];
    const u16* p2_pw   = (const u16*)d_in[12];
    const u16* p2_pb   = (const u16*)d_in[13];
    const u16* p2_wih  = (const u16*)d_in[14];
    const u16* p2_whh  = (const u16*)d_in[15];
    const u16* p2_bih  = (const u16*)d_in[16];
    const u16* p2_bhh  = (const u16*)d_in[17];
    const u16* p2_llw  = (const u16*)d_in[18];
    const u16* p2_llb  = (const u16*)d_in[19];
    const u16* p2_lrw  = (const u16*)d_in[20];
    const u16* lin1w   = (const u16*)d_in[21];
    const u16* lin1b   = (const u16*)d_in[22];
    const u16* lin2w   = (const u16*)d_in[23];
    const u16* lin2b   = (const u16*)d_in[24];
    const u16* lin3w   = (const u16*)d_in[25];
    const u16* lin3b   = (const u16*)d_in[26];
    (void)n_in; (void)ws_size;

    const int N  = in_sizes[0] / 64;     // 50000
    const int E2 = in_sizes[1];          // 1600000
    const int* srcIdx = edge;

    // workspace: scaled weights 128KB @0; xp1 @1MB; H @8MB; Y1 @15MB; xp2 @22MB
    char* w = (char*)d_ws;
    u16* wss   = (u16*)(w);
    u16* xp1   = (u16*)(w + 1u  * 1024 * 1024);
    u16* bufH  = (u16*)(w + 8u  * 1024 * 1024);
    u16* bufY1 = (u16*)(w + 15u * 1024 * 1024);
    u16* xp2   = (u16*)(w + 22u * 1024 * 1024);
    u16* wih1s = wss;
    u16* whh1s = wss + 16384;
    u16* wih2s = wss + 32768;
    u16* whh2s = wss + 49152;

    float* out_h    = (float*)d_out;
    float* out_edge = (float*)d_out + (size_t)N * 64;
    (void)out_size;

    const int gb = (N + 63) / 64;        // 782
    const int n4 = E2 / 4;
    const int eb = (n4 + 255) / 256;     // 1563

    dim3 block(256);

    hipLaunchKernelGGL(k_pre, dim3(gb + eb + 4), block, 0, stream,
                       x, p1_pw, p1_pb, xp1, N, gb,
                       edge, out_edge, n4, eb,
                       p1_wih, p1_whh, p2_wih, p2_whh, wss);
    hipLaunchKernelGGL(lstm_kernel, dim3(gb), block, 0, stream,
                       xp1, srcIdx, wih1s, whh1s, p1_bih, p1_bhh, bufH, N);
    hipLaunchKernelGGL(k_mid, dim3(gb), block, 0, stream,
                       bufH, x, p1_llw, p1_llb, p1_lrw, p2_pw, p2_pb, bufY1, xp2, N);
    hipLaunchKernelGGL(lstm_kernel, dim3(gb), block, 0, stream,
                       xp2, srcIdx, wih2s, whh2s, p2_bih, p2_bhh, bufH, N);
    hipLaunchKernelGGL(k_post, dim3(gb), block, 0, stream,
                       bufH, bufY1, p2_llw, p2_llb, p2_lrw,
                       lin1w, lin1b, lin2w, lin2b, lin3w, lin3b, out_h, N);
}